// Round 6
// baseline (297.160 us; speedup 1.0000x reference)
//
#include <hip/hip_runtime.h>

#define D 128
#define EPSV 1e-5f

typedef __attribute__((ext_vector_type(8))) short bf16x8;
typedef __attribute__((ext_vector_type(4))) float f32x4;

__device__ __forceinline__ short f2bf(float f){
  unsigned u = __float_as_uint(f);
  u += 0x7fffu + ((u >> 16) & 1u);          // RNE
  return (short)(u >> 16);
}
__device__ __forceinline__ float bflo(unsigned u){ return __uint_as_float(u << 16); }
__device__ __forceinline__ float bfhi(unsigned u){ return __uint_as_float(u & 0xffff0000u); }
__device__ __forceinline__ float bf2f(short s){ return __uint_as_float(((unsigned)(unsigned short)s) << 16); }
__device__ __forceinline__ unsigned packbf(float a, float b){
  unsigned lo = (unsigned short)f2bf(a);
  unsigned hi = (unsigned short)f2bf(b);
  return lo | (hi << 16);
}

// Fused init: detect int64-vs-int32 edge layout (block 0), zero deg/fill/gpart/
// scan-flags, transpose W1,W2 -> bf16 [out_col][k] (16B-contiguous B frags).
__global__ void k_init(int N, int E, const int* __restrict__ ei, int* __restrict__ flag,
                       int* __restrict__ deg, int* __restrict__ fill, float* __restrict__ gpart,
                       int* __restrict__ sflg,
                       const float* __restrict__ W1, const float* __restrict__ W2,
                       short* __restrict__ w1t, short* __restrict__ w2t){
  int i = blockIdx.x*blockDim.x + threadIdx.x;
  if (i < N){ deg[i] = 0; fill[i] = 0; }
  if (i < D*D){
    int j = i >> 7, k = i & 127;
    w1t[i] = f2bf(W1[k*D + j]);
    w2t[i] = f2bf(W2[k*D + j]);
  }
  if (i < 2048) gpart[i] = 0.f;
  if (i < 128) sflg[i] = 0;
  if (blockIdx.x == 0){
    __shared__ int any;
    int t = threadIdx.x;
    if (t == 0) any = 0;
    __syncthreads();
    if (2*t+1 < 2*E && ei[2*t+1] != 0) atomicOr(&any, 1);
    __syncthreads();
    if (t == 0) flag[0] = (any == 0) ? 1 : 0;   // 1 => int64 layout
  }
}

// One-kernel scan: per-1024-node block sums + decoupled lookback (device-scope
// atomics; all 98 blocks co-resident => deadlock-free). Writes rowp AND dinv.
__global__ void k_scan(const int* __restrict__ deg, int N, int* __restrict__ rowp,
                       float* __restrict__ dinv, int* __restrict__ s_agg,
                       int* __restrict__ s_inc, int* __restrict__ s_flg){
  __shared__ int sh[256];
  __shared__ int s_ex;
  int b = blockIdx.x, t = threadIdx.x;
  int base = b*1024 + t*4;
  int c0 = (base+0 < N) ? deg[base+0] : 0;
  int c1 = (base+1 < N) ? deg[base+1] : 0;
  int c2 = (base+2 < N) ? deg[base+2] : 0;
  int c3 = (base+3 < N) ? deg[base+3] : 0;
  int s = c0 + c1 + c2 + c3;
  sh[t] = s; __syncthreads();
  for (int d = 1; d < 256; d <<= 1){
    int v = (t >= d) ? sh[t-d] : 0;
    __syncthreads();
    sh[t] += v;
    __syncthreads();
  }
  int total = sh[255];
  if (t == 0){
    atomicExch(&s_agg[b], total);
    __threadfence();
    atomicExch(&s_flg[b], 1);
    int ex = 0;
    for (int i = b-1; i >= 0; ){
      int f;
      while ((f = atomicAdd(&s_flg[i], 0)) == 0) __builtin_amdgcn_s_sleep(1);
      if (f == 2){ ex += atomicAdd(&s_inc[i], 0); break; }
      ex += atomicAdd(&s_agg[i], 0); --i;
    }
    atomicExch(&s_inc[b], ex + total);
    __threadfence();
    atomicExch(&s_flg[b], 2);
    s_ex = ex;
  }
  __syncthreads();
  int o = sh[t] - s + s_ex;
  if (base+0 < N){ rowp[base+0] = o; dinv[base+0] = rsqrtf((float)(c0+1)); } o += c0;
  if (base+1 < N){ rowp[base+1] = o; dinv[base+1] = rsqrtf((float)(c1+1)); } o += c1;
  if (base+2 < N){ rowp[base+2] = o; dinv[base+2] = rsqrtf((float)(c2+1)); } o += c2;
  if (base+3 < N){ rowp[base+3] = o; dinv[base+3] = rsqrtf((float)(c3+1)); }
}

__global__ void k_scatter(const int* __restrict__ ei, int E, const int* __restrict__ flag,
                          const int* __restrict__ rowp, int* __restrict__ fill,
                          const float* __restrict__ dinv, int2* __restrict__ epack){
  int e = blockIdx.x*blockDim.x + threadIdx.x;
  if (e >= E) return;
  int s, d;
  if (flag[0]){ s = ei[2*e]; d = ei[2*E + 2*e]; }
  else        { s = ei[e];   d = ei[E + e];     }
  int pos = rowp[d] + atomicAdd(&fill[d], 1);
  int2 ev; ev.x = s; ev.y = __float_as_int(dinv[s] * dinv[d]);
  epack[pos] = ev;
}

// GEMM v6: B (128x128 bf16 = 32KB) in LDS, XOR-swizzled. MFMA operands swapped
// (mfma(b,a) => C^T frags); epilogue bounces through per-wave swizzled LDS tile
// for dwordx4 coalesced row stores. launch_bounds(256,3): 3 blocks/CU (LDS
// 3x48KB=144<=160KB, VGPR cap ~170). MODE 1 = f32 A (cast) + degree-count
// blocks appended (blockIdx >= ngemmb). MODE 2 = bf16 A with fused BN+ReLU;
// scale/shift computed per-block from gpart.
template<int MODE>
__global__ __launch_bounds__(256, 3) void k_gemm(const void* __restrict__ A,
                                const short* __restrict__ BT, short* __restrict__ C, int N,
                                const float* __restrict__ gpart, const float* __restrict__ gamma,
                                const float* __restrict__ beta,
                                const int* __restrict__ ei, int E, const int* __restrict__ flag,
                                int* __restrict__ deg, int ngemmb){
  if (MODE == 1 && (int)blockIdx.x >= ngemmb){
    int cb = blockIdx.x - ngemmb;
    int e0 = cb*1024 + threadIdx.x;
    int f = flag[0];
    #pragma unroll
    for (int r = 0; r < 4; ++r){
      int e = e0 + r*256;
      if (e < E){
        int d = f ? ei[2*E + 2*e] : ei[E + e];
        atomicAdd(&deg[d], 1);
      }
    }
    return;
  }
  __shared__ short ldsB[16384];     // [row=col-of-W 128][k 128], chunk-swizzled
  __shared__ short ldsC[4*2048];    // per-wave 16x128 epilogue tile
  __shared__ __align__(16) float s_sc[128];
  __shared__ __align__(16) float s_sh[128];
  int w = threadIdx.x >> 6;
  int lane = threadIdx.x & 63;
  int m = lane & 15, quad = lane >> 4;

  if (MODE == 2 && threadIdx.x < 128){
    int f = threadIdx.x;
    float s = 0.f, q = 0.f;
    #pragma unroll
    for (int i = 0; i < 8; ++i){ s += gpart[i*256 + f]; q += gpart[i*256 + 128 + f]; }
    float inv = 1.f / (float)N;
    float mean = s * inv;
    float var  = q * inv - mean*mean;   // biased, matches torch BN batch stats
    float sc = gamma[f] * rsqrtf(var + EPSV);
    s_sc[f] = sc;
    s_sh[f] = beta[f] - mean * sc;
  }
  // stage B into LDS with chunk XOR swizzle
  {
    const bf16x8* BTv = (const bf16x8*)BT;
    bf16x8* Bw = (bf16x8*)ldsB;
    for (int g = threadIdx.x; g < 2048; g += 256){
      int row = g >> 4, ch = g & 15;
      Bw[row*16 + (ch ^ (row & 15))] = BTv[g];
    }
  }
  __syncthreads();
  const bf16x8* Bv = (const bf16x8*)ldsB;
  short* cw = ldsC + w*2048;

  int tiles = (N + 31) >> 5;
  int wid = blockIdx.x*4 + w;
  int wstride = ngemmb*4;
  for (int tile = wid; tile < tiles; tile += wstride){
    int r0 = tile << 5;
    bf16x8 a[2][4];
    #pragma unroll
    for (int g = 0; g < 2; ++g){
      int row = r0 + g*16 + m;
      if (row >= N) row = N - 1;
      #pragma unroll
      for (int kc = 0; kc < 4; ++kc){
        int k0 = kc*32 + quad*8;
        if (MODE == 1){
          const float* Af = (const float*)A + (size_t)row*D + k0;
          float4 u = *(const float4*)Af;
          float4 v = *(const float4*)(Af + 4);
          bf16x8 tv;
          tv[0]=f2bf(u.x); tv[1]=f2bf(u.y); tv[2]=f2bf(u.z); tv[3]=f2bf(u.w);
          tv[4]=f2bf(v.x); tv[5]=f2bf(v.y); tv[6]=f2bf(v.z); tv[7]=f2bf(v.w);
          a[g][kc] = tv;
        } else {
          bf16x8 raw = *(const bf16x8*)((const short*)A + (size_t)row*D + k0);
          float4 s0v = *(const float4*)(s_sc + k0);
          float4 s1v = *(const float4*)(s_sc + k0 + 4);
          float4 h0v = *(const float4*)(s_sh + k0);
          float4 h1v = *(const float4*)(s_sh + k0 + 4);
          bf16x8 tv;
          tv[0] = f2bf(fmaxf(fmaf(bf2f(raw[0]), s0v.x, h0v.x), 0.f));
          tv[1] = f2bf(fmaxf(fmaf(bf2f(raw[1]), s0v.y, h0v.y), 0.f));
          tv[2] = f2bf(fmaxf(fmaf(bf2f(raw[2]), s0v.z, h0v.z), 0.f));
          tv[3] = f2bf(fmaxf(fmaf(bf2f(raw[3]), s0v.w, h0v.w), 0.f));
          tv[4] = f2bf(fmaxf(fmaf(bf2f(raw[4]), s1v.x, h1v.x), 0.f));
          tv[5] = f2bf(fmaxf(fmaf(bf2f(raw[5]), s1v.y, h1v.y), 0.f));
          tv[6] = f2bf(fmaxf(fmaf(bf2f(raw[6]), s1v.z, h1v.z), 0.f));
          tv[7] = f2bf(fmaxf(fmaf(bf2f(raw[7]), s1v.w, h1v.w), 0.f));
          a[g][kc] = tv;
        }
      }
    }
    f32x4 acc[2][8];
    #pragma unroll
    for (int g = 0; g < 2; ++g)
      #pragma unroll
      for (int c = 0; c < 8; ++c) acc[g][c] = (f32x4){0.f,0.f,0.f,0.f};
    #pragma unroll
    for (int kc = 0; kc < 4; ++kc){
      bf16x8 bb[8];
      #pragma unroll
      for (int c = 0; c < 8; ++c)
        bb[c] = Bv[(c*16 + m)*16 + ((kc*4 + quad) ^ m)];
      #pragma unroll
      for (int g = 0; g < 2; ++g)
        #pragma unroll
        for (int c = 0; c < 8; ++c)
          acc[g][c] = __builtin_amdgcn_mfma_f32_16x16x32_bf16(bb[c], a[g][kc], acc[g][c], 0, 0, 0);
    }
    // epilogue: per 16-row group, pack -> LDS (swizzled) -> coalesced dwordx4
    #pragma unroll
    for (int g = 0; g < 2; ++g){
      #pragma unroll
      for (int c = 0; c < 8; ++c){
        uint2 v;
        v.x = packbf(acc[g][c][0], acc[g][c][1]);
        v.y = packbf(acc[g][c][2], acc[g][c][3]);
        int x = c*2 + (quad >> 1);
        *(uint2*)&cw[m*128 + ((x ^ m) << 3) + ((quad & 1) << 2)] = v;
      }
      asm volatile("s_waitcnt lgkmcnt(0)" ::: "memory");
      #pragma unroll
      for (int rg = 0; rg < 4; ++rg){
        int lrow = rg*4 + quad;
        int rr = r0 + g*16 + lrow;
        uint4 v = *(const uint4*)&cw[lrow*128 + ((m ^ lrow) << 3)];
        if (rr < N) *(uint4*)(C + (size_t)rr*D + m*8) = v;
      }
      asm volatile("s_waitcnt lgkmcnt(0)" ::: "memory");
    }
  }
}

// Aggregation v4: TWO nodes per wave (lanes 0-31 = node 2pr, lanes 32-63 =
// node 2pr+1), 4 features per lane, dwordx2 gathers (512B per instruction
// across both halves). Per-half shfl broadcast via lane = (p&32)+j+t. Paired
// nodes have adjacent CSR ranges and adjacent output rows. OUTF32==0 also
// accumulates BN statistics (4 features/lane -> LDS atomics -> gpart).
template<int OUTF32>
__global__ __launch_bounds__(256) void k_agg(const short* __restrict__ H, const int* __restrict__ rowp,
        const int* __restrict__ deg, const int2* __restrict__ epack, const float* __restrict__ dinv,
        const float* __restrict__ bias, void* __restrict__ out, int N, float* __restrict__ gpart){
  int w = threadIdx.x >> 6, p = threadIdx.x & 63;
  int q = p & 31, hb32 = p & 32;
  int wid = blockIdx.x*4 + w, wstride = gridDim.x*4;
  const uint2* Hu2 = (const uint2*)H;
  float S0=0.f,S1=0.f,S2=0.f,S3=0.f,Q0=0.f,Q1=0.f,Q2=0.f,Q3=0.f;
  float4 b4 = {0.f,0.f,0.f,0.f};
  if (OUTF32) b4 = *(const float4*)(bias + 4*q);
  int pairs = (N + 1) >> 1;
  for (int pr = wid; pr < pairs; pr += wstride){
    int n = 2*pr + (p >> 5);
    bool valid = n < N;
    int start = 0, cnt = 0; float d1 = 0.f;
    if (valid){ start = rowp[n]; cnt = deg[n]; d1 = dinv[n]; }
    uint2 self; self.x = 0; self.y = 0;
    if (valid) self = Hu2[(size_t)n*32 + q];
    int2 ev; ev.x = 0; ev.y = 0;
    if (q < (cnt < 32 ? cnt : 32)) ev = epack[start + q];
    int co = __shfl(cnt, p ^ 32);
    int maxcF = cnt > co ? cnt : co;
    int maxc = maxcF < 32 ? maxcF : 32;
    float w0 = d1*d1;
    float a0 = w0*bflo(self.x), a1 = w0*bfhi(self.x);
    float a2 = w0*bflo(self.y), a3 = w0*bfhi(self.y);
    for (int j = 0; j < maxc; j += 8){
      int ss[8]; float ff[8];
      #pragma unroll
      for (int t = 0; t < 8; ++t){
        ss[t] = __shfl(ev.x, hb32 + j + t);
        ff[t] = __int_as_float(__shfl(ev.y, hb32 + j + t));
      }
      uint2 uu[8];
      #pragma unroll
      for (int t = 0; t < 8; ++t) uu[t] = Hu2[(size_t)ss[t]*32 + q];
      #pragma unroll
      for (int t = 0; t < 8; ++t){
        a0 = fmaf(ff[t], bflo(uu[t].x), a0); a1 = fmaf(ff[t], bfhi(uu[t].x), a1);
        a2 = fmaf(ff[t], bflo(uu[t].y), a2); a3 = fmaf(ff[t], bfhi(uu[t].y), a3);
      }
    }
    // rare overflow (deg > 32)
    for (int base2 = 32; base2 < maxcF; base2 += 32){
      int2 evx; evx.x = 0; evx.y = 0;
      int rem = cnt - base2;
      if (rem > 0 && q < (rem < 32 ? rem : 32)) evx = epack[start + base2 + q];
      int mb = maxcF - base2; mb = mb < 32 ? mb : 32;
      for (int j = 0; j < mb; j += 8){
        #pragma unroll
        for (int t = 0; t < 8; ++t){
          int sx = __shfl(evx.x, hb32 + j + t);
          float fx = __int_as_float(__shfl(evx.y, hb32 + j + t));
          uint2 ux = Hu2[(size_t)sx*32 + q];
          a0 = fmaf(fx, bflo(ux.x), a0); a1 = fmaf(fx, bfhi(ux.x), a1);
          a2 = fmaf(fx, bflo(ux.y), a2); a3 = fmaf(fx, bfhi(ux.y), a3);
        }
      }
    }
    if (OUTF32){
      if (valid){
        float4 r; r.x = a0 + b4.x; r.y = a1 + b4.y; r.z = a2 + b4.z; r.w = a3 + b4.w;
        *(float4*)((float*)out + (size_t)n*D + 4*q) = r;
      }
    } else {
      if (valid){
        uint2 r; r.x = packbf(a0, a1); r.y = packbf(a2, a3);
        ((uint2*)out)[(size_t)n*32 + q] = r;
        S0 += a0; Q0 += a0*a0; S1 += a1; Q1 += a1*a1;
        S2 += a2; Q2 += a2*a2; S3 += a3; Q3 += a3*a3;
      }
    }
  }
  if (!OUTF32){
    __shared__ float ls[256];
    ls[threadIdx.x] = 0.f; __syncthreads();
    int f = 4*q;
    atomicAdd(&ls[f+0], S0); atomicAdd(&ls[f+1], S1);
    atomicAdd(&ls[f+2], S2); atomicAdd(&ls[f+3], S3);
    atomicAdd(&ls[128+f+0], Q0); atomicAdd(&ls[128+f+1], Q1);
    atomicAdd(&ls[128+f+2], Q2); atomicAdd(&ls[128+f+3], Q3);
    __syncthreads();
    atomicAdd(&gpart[(blockIdx.x & 7)*256 + threadIdx.x], ls[threadIdx.x]);
  }
}

extern "C" void kernel_launch(void* const* d_in, const int* in_sizes, int n_in,
                              void* d_out, int out_size, void* d_ws, size_t ws_size,
                              hipStream_t stream){
  const float* x   = (const float*)d_in[0];
  const int*   ei  = (const int*)  d_in[1];
  const float* W1  = (const float*)d_in[2];
  // d_in[3] = b1: cancels in BatchNorm, unused
  const float* g1  = (const float*)d_in[4];
  const float* be1 = (const float*)d_in[5];
  const float* W2  = (const float*)d_in[6];
  const float* b2  = (const float*)d_in[7];
  float* out = (float*)d_out;
  int N = in_sizes[0] / D;
  int E = in_sizes[1] / 2;

  char* w = (char*)d_ws;
  auto carve = [&](size_t bytes)->char*{ char* p = w; w += (bytes + 255) & ~(size_t)255; return p; };
  int*   flag  = (int*)  carve(256);
  int*   degA  = (int*)  carve((size_t)N*4);
  int*   fillA = (int*)  carve((size_t)N*4);
  float* dinvA = (float*)carve((size_t)N*4);
  int*   rowp  = (int*)  carve((size_t)N*4);
  int*   sagg  = (int*)  carve(512);
  int*   sinc  = (int*)  carve(512);
  int*   sflg  = (int*)  carve(512);
  int2*  epack = (int2*) carve((size_t)E*8);
  float* gpart = (float*)carve(2048*4);
  short* w1t   = (short*)carve((size_t)D*D*2);
  short* w2t   = (short*)carve((size_t)D*D*2);
  short* h1    = (short*)carve((size_t)N*D*2);   // GEMM1 out; reused as GEMM2 out
  short* hb    = (short*)carve((size_t)N*D*2);   // agg1 out (pre-BN h)

  const int TB = 256;
  int EB  = (E + TB - 1) / TB;
  int NBt = (N + TB - 1) / TB;
  int NB1024 = (N + 1023) / 1024;
  int GEMMB = 768;                 // 3 blocks/CU (48KB LDS, launch_bounds(256,3))
  int CNTB  = (E + 1023) / 1024;   // count blocks appended to gemm1 grid
  int AGGB  = 2048;                // 8 blocks/CU = 32 waves/CU

  k_init    <<<NBt, TB, 0, stream>>>(N, E, ei, flag, degA, fillA, gpart, sflg, W1, W2, w1t, w2t);
  k_gemm<1> <<<GEMMB + CNTB, 256, 0, stream>>>(x, w1t, h1, N, nullptr, nullptr, nullptr,
                                               ei, E, flag, degA, GEMMB);
  k_scan    <<<NB1024, 256, 0, stream>>>(degA, N, rowp, dinvA, sagg, sinc, sflg);
  k_scatter <<<EB, TB, 0, stream>>>(ei, E, flag, rowp, fillA, dinvA, epack);
  k_agg<0>  <<<AGGB, 256, 0, stream>>>(h1, rowp, degA, epack, dinvA, nullptr, hb, N, gpart);
  k_gemm<2> <<<GEMMB, 256, 0, stream>>>(hb, w2t, h1, N, gpart, g1, be1,
                                        nullptr, 0, nullptr, nullptr, GEMMB);
  k_agg<1>  <<<AGGB, 256, 0, stream>>>(h1, rowp, degA, epack, dinvA, b2, out, N, nullptr);
}